// Round 3
// baseline (302.681 us; speedup 1.0000x reference)
//
#include <hip/hip_runtime.h>

// Bidirectional GRU (H=32, input=1, B=2048, T=512) + MLP head, fully fused.
//
// Reference takes out[:, -1, :] = concat(h_fwd after T steps, h_bwd after ONE
// step from h0=0 on x[T-1]) -> only the forward scan is sequential; W_hh_b is
// entirely unused.
//
// R3 design (after R1/R2 post-mortem: vf2 w[16] arrays were NEVER promoted to
// registers -- promote-alloca size budget -- so weights lived in scratch and
// every step re-read them: FETCH_SIZE 2.15 GB, VGPR=80 regardless of
// __launch_bounds__):
//   * Weights are 12 individually-NAMED vf4 variables (no arrays -> guaranteed
//     register residency).
//   * K-split: 64 lanes per batch row. Lane (i = L&31, k = L>>5) computes the
//     16-wide K-half of the r/z/n dots for output i; halves combined with one
//     __shfl_xor(.,32) per gate. Halves per-lane FMA work AND doubles wave
//     count to 2048 = 2 waves/SIMD so latency chains of one wave hide behind
//     the other.
//   * X row staged to LDS once; inner loop touches no global memory.
//   * h broadcast per step through two LDS copies (one per K-half) so all 64
//     lanes write unconditionally (no exec masking); 2-way bank aliasing
//     between copies is free on gfx950.

typedef float vf4 __attribute__((ext_vector_type(4)));

#define TT 512
#define HH 32

__device__ __forceinline__ float sigm(float a) {
  return 1.0f / (1.0f + __expf(-a));
}
// tanh(a) = 1 - 2/(exp(2a)+1); correct limits at +/-inf in fp32.
__device__ __forceinline__ float tanh_(float a) {
  return 1.0f - 2.0f / (1.0f + __expf(2.0f * a));
}

__global__ __launch_bounds__(256, 2)
void gru_bidir_head(const float* __restrict__ X,
                    const float* __restrict__ Wih_f, const float* __restrict__ Whh_f,
                    const float* __restrict__ bih_f, const float* __restrict__ bhh_f,
                    const float* __restrict__ Wih_b,
                    const float* __restrict__ bih_b, const float* __restrict__ bhh_b,
                    const float* __restrict__ W1, const float* __restrict__ b1,
                    const float* __restrict__ W2, const float* __restrict__ b2,
                    float* __restrict__ out)
{
  __shared__ float xbuf[4][TT];        // staged input rows (8 KB)
  __shared__ float hbuf[4][2][HH];     // [row][K-half copy][i]  (1 KB)

  const int L = threadIdx.x & 63;      // lane in wave
  const int w = threadIdx.x >> 6;      // wave in block = row slot (0..3)
  const int i = L & 31;                // output element owned by this lane
  const int k = L >> 5;                // K-half (h[0:16) vs h[16:32))
  const int b = (blockIdx.x << 2) + w; // global batch row

  // --- stage this wave's X row into LDS (coalesced, 2 x float4 per lane) ---
  const vf4* Xrow4 = (const vf4*)(X + (size_t)b * TT);
  vf4* xb4 = (vf4*)&xbuf[w][0];
  xb4[L]      = Xrow4[L];
  xb4[64 + L] = Xrow4[64 + L];

  // --- per-lane weights: W_hh rows {i, 32+i, 64+i}, cols [16k, 16k+16) ---
  // NAMED vf4s, no arrays: must stay in VGPRs (promote-alloca can't bail).
  const vf4* W4 = (const vf4*)Whh_f;             // row stride = 8 vf4
  const int br = (i)        * 8 + k * 4;
  const int bz = (HH + i)   * 8 + k * 4;
  const int bn = (2*HH + i) * 8 + k * 4;
  const vf4 wr0 = W4[br+0], wr1 = W4[br+1], wr2 = W4[br+2], wr3 = W4[br+3];
  const vf4 wz0 = W4[bz+0], wz1 = W4[bz+1], wz2 = W4[bz+2], wz3 = W4[bz+3];
  const vf4 wn0 = W4[bn+0], wn1 = W4[bn+1], wn2 = W4[bn+2], wn3 = W4[bn+3];

  const float wir = Wih_f[i], wiz = Wih_f[HH + i], win = Wih_f[2*HH + i];
  const float brs = bih_f[i]      + bhh_f[i];      // fold b_ih+b_hh for r
  const float bzs = bih_f[HH + i] + bhh_f[HH + i]; // fold for z
  const float bin = bih_f[2*HH + i];               // n keeps them separate:
  const float bhn = bhh_f[2*HH + i];               // n = tanh(xn + r*(dot+bhn))

  float h = 0.0f;
  hbuf[w][k][i] = 0.0f;                // both copies zeroed
  __builtin_amdgcn_wave_barrier();

  const vf4* hv = (const vf4*)&hbuf[w][k][0];  // this lane's K-half copy

  #pragma unroll 1
  for (int t = 0; t < TT; ++t) {
    const float x = xbuf[w][t];                  // broadcast ds_read_b32

    const vf4 h0 = hv[0], h1 = hv[1], h2 = hv[2], h3 = hv[3];

    vf4 ar4 = h0 * wr0;
    vf4 az4 = h0 * wz0;
    vf4 an4 = h0 * wn0;
    ar4 = __builtin_elementwise_fma(h1, wr1, ar4);
    az4 = __builtin_elementwise_fma(h1, wz1, az4);
    an4 = __builtin_elementwise_fma(h1, wn1, an4);
    ar4 = __builtin_elementwise_fma(h2, wr2, ar4);
    az4 = __builtin_elementwise_fma(h2, wz2, az4);
    an4 = __builtin_elementwise_fma(h2, wn2, an4);
    ar4 = __builtin_elementwise_fma(h3, wr3, ar4);
    az4 = __builtin_elementwise_fma(h3, wz3, az4);
    an4 = __builtin_elementwise_fma(h3, wn3, an4);

    float arp = (ar4.x + ar4.y) + (ar4.z + ar4.w);
    float azp = (az4.x + az4.y) + (az4.z + az4.w);
    float anp = (an4.x + an4.y) + (an4.z + an4.w);
    arp += __shfl_xor(arp, 32, 64);              // combine K-halves
    azp += __shfl_xor(azp, 32, 64);
    anp += __shfl_xor(anp, 32, 64);

    const float r = sigm(__builtin_fmaf(x, wir, brs) + arp);
    const float z = sigm(__builtin_fmaf(x, wiz, bzs) + azp);
    const float n = tanh_(__builtin_fmaf(r, anp + bhn, __builtin_fmaf(x, win, bin)));
    h = __builtin_fmaf(z, h - n, n);             // (1-z)*n + z*h

    hbuf[w][k][i] = h;                           // refresh this half's copy
    __builtin_amdgcn_wave_barrier();             // wave-synchronous LDS
  }

  // --- backward direction: exactly ONE GRU step from h0=0 on x[T-1] ---
  const float xl  = xbuf[w][TT - 1];
  const float rb  = sigm(__builtin_fmaf(xl, Wih_b[i],        bih_b[i]        + bhh_b[i]));
  const float zb  = sigm(__builtin_fmaf(xl, Wih_b[HH + i],   bih_b[HH + i]   + bhh_b[HH + i]));
  const float xnb =       __builtin_fmaf(xl, Wih_b[2*HH + i], bih_b[2*HH + i]);
  const float nb  = tanh_(__builtin_fmaf(rb, bhh_b[2*HH + i], xnb));
  const float hb  = nb - zb * nb;                // (1-zb)*nb + zb*0

  // copy0 keeps h_f (last loop write); overwrite copy1 with h_b ->
  // hbuf[w][0..63] = [h_f(32) | h_b(32)] contiguous.
  if (k == 1) hbuf[w][1][i] = hb;
  __builtin_amdgcn_wave_barrier();

  // --- MLP head: sigmoid(W2 @ relu(W1 @ [h_f,h_b] + b1) + b2) ---
  const int j = L & 15;                          // lanes 16..63 duplicate
  const vf4* W1r = (const vf4*)(W1 + j * 64);
  const vf4* hc  = (const vf4*)&hbuf[w][0][0];
  vf4 a4 = W1r[0] * hc[0];
  #pragma unroll
  for (int q = 1; q < 16; ++q)
    a4 = __builtin_elementwise_fma(W1r[q], hc[q], a4);
  float acc = b1[j] + (a4.x + a4.y) + (a4.z + a4.w);
  float h1 = fmaxf(acc, 0.0f) * W2[j];
  h1 += __shfl_down(h1, 8, 16);
  h1 += __shfl_down(h1, 4, 16);
  h1 += __shfl_down(h1, 2, 16);
  h1 += __shfl_down(h1, 1, 16);
  if (L == 0) out[b] = sigm(h1 + b2[0]);
}

extern "C" void kernel_launch(void* const* d_in, const int* in_sizes, int n_in,
                              void* d_out, int out_size, void* d_ws, size_t ws_size,
                              hipStream_t stream) {
  const float* X     = (const float*)d_in[0];
  const float* Wih_f = (const float*)d_in[1];
  const float* Whh_f = (const float*)d_in[2];
  const float* bih_f = (const float*)d_in[3];
  const float* bhh_f = (const float*)d_in[4];
  const float* Wih_b = (const float*)d_in[5];
  // d_in[6] = W_hh_b: unused — backward direction runs exactly one step from h0=0.
  const float* bih_b = (const float*)d_in[7];
  const float* bhh_b = (const float*)d_in[8];
  const float* W1    = (const float*)d_in[9];
  const float* b1    = (const float*)d_in[10];
  const float* W2    = (const float*)d_in[11];
  const float* b2    = (const float*)d_in[12];
  float* out = (float*)d_out;

  // 2048 rows, 1 row per wave (64 lanes, K-split), 4 rows per 256-thread block
  // -> 512 blocks = 2 blocks/CU = 2 waves/SIMD.
  gru_bidir_head<<<512, 256, 0, stream>>>(X, Wih_f, Whh_f, bih_f, bhh_f,
                                          Wih_b, bih_b, bhh_b, W1, b1, W2, b2, out);
}

// Round 4
// 294.958 us; speedup vs baseline: 1.0262x; 1.0262x over previous
//
#include <hip/hip_runtime.h>

// Bidirectional GRU (H=32, input=1, B=2048, T=512) + MLP head, fully fused.
//
// Reference takes out[:, -1, :] = concat(h_fwd after T steps, h_bwd after ONE
// step from h0=0 on x[T-1]) -> only the forward scan is sequential; W_hh_b is
// entirely unused.
//
// R4 design. R1-R3 post-mortem: invariant (__restrict__ const) weight loads
// are REMATERIALIZABLE, so the scheduler demotes them and re-loads from
// memory inside the t-loop to chase occupancy (R3: VGPR_Count=48 < the 48
// weight regs alone).  Fix: pin each weight value with an empty inline-asm
// "+v" constraint -- inline-asm defs are never remat'd, forcing residency.
//
//   * 64 lanes per batch row, gate-hybrid split: lane (i, k=0) computes the
//     full 32-K r-dot + n-dot half [0:16); lane (i, k=1) full z-dot + n-dot
//     half [16:32).  One shfl_xor(32) exchanges rdot/zdot, one more sums the
//     n halves (2 shfls/step vs 3 for pure K-split).
//   * Weights as 24 pinned vf2 -> v_pk_fma_f32 one-to-one (24 pk FMA/step).
//   * t-loop unrolled x4: one broadcast ds_read_b128 of x per 4 steps.
//   * h kept per-lane + dual LDS copy (one per K-half) written
//     unconditionally; broadcast ds_read_b128, 2-way bank alias = free.
//   * 2048 waves = 2 waves/SIMD so LDS/exp latency of one wave hides behind
//     the other.  No __syncthreads anywhere (wave-private LDS rows).

typedef float vf2 __attribute__((ext_vector_type(2)));
typedef float vf4 __attribute__((ext_vector_type(4)));

#define TT 512
#define HH 32

// Make a value opaque to the register allocator: inline-asm defs are not
// rematerializable, so these stay in VGPRs across the loop.
#define PIN(v) asm volatile("" : "+v"(v))

__device__ __forceinline__ float sigm(float a) {
  return 1.0f / (1.0f + __expf(-a));
}
// tanh(a) = 1 - 2/(exp(2a)+1); correct limits at +/-inf in fp32.
__device__ __forceinline__ float tanh_(float a) {
  return 1.0f - 2.0f / (1.0f + __expf(2.0f * a));
}

__global__ __launch_bounds__(256, 2)
void gru_bidir_head(const float* __restrict__ X,
                    const float* __restrict__ Wih_f, const float* __restrict__ Whh_f,
                    const float* __restrict__ bih_f, const float* __restrict__ bhh_f,
                    const float* __restrict__ Wih_b,
                    const float* __restrict__ bih_b, const float* __restrict__ bhh_b,
                    const float* __restrict__ W1, const float* __restrict__ b1,
                    const float* __restrict__ W2, const float* __restrict__ b2,
                    float* __restrict__ out)
{
  __shared__ float xbuf[4][TT];        // staged input rows (8 KB)
  __shared__ float hbuf[4][2][HH];     // [row][K-half copy][i] (1 KB)
  __shared__ float obuf[4][64];        // [row][h_f(32) | h_b(32)] (1 KB)

  const int L = threadIdx.x & 63;      // lane in wave
  const int w = threadIdx.x >> 6;      // wave in block = row slot (0..3)
  const int i = L & 31;                // output element owned by this lane
  const int k = L >> 5;                // half: k=0 -> r-gate + n[0:16), k=1 -> z-gate + n[16:32)
  const int b = (blockIdx.x << 2) + w; // global batch row

  // --- stage this wave's X row into LDS (coalesced, 2 x float4 per lane) ---
  const vf4* Xrow4 = (const vf4*)(X + (size_t)b * TT);
  vf4* xb4 = (vf4*)&xbuf[w][0];
  xb4[L]      = Xrow4[L];
  xb4[64 + L] = Xrow4[64 + L];

  // --- per-lane weights (PINNED) ---
  // full gate row: r-row i (k=0) or z-row HH+i (k=1); n half-row [16k,16k+16)
  const vf2* W2p = (const vf2*)Whh_f;                // row stride = 16 vf2
  const int gbase = (k ? (HH + i) : i) * 16;
  const int nbase = (2 * HH + i) * 16 + k * 8;
  vf2 g0 = W2p[gbase+0],  g1 = W2p[gbase+1],  g2 = W2p[gbase+2],  g3 = W2p[gbase+3];
  vf2 g4 = W2p[gbase+4],  g5 = W2p[gbase+5],  g6 = W2p[gbase+6],  g7 = W2p[gbase+7];
  vf2 g8 = W2p[gbase+8],  g9 = W2p[gbase+9],  gA = W2p[gbase+10], gB = W2p[gbase+11];
  vf2 gC = W2p[gbase+12], gD = W2p[gbase+13], gE = W2p[gbase+14], gF = W2p[gbase+15];
  vf2 n0 = W2p[nbase+0],  n1 = W2p[nbase+1],  n2 = W2p[nbase+2],  n3 = W2p[nbase+3];
  vf2 n4 = W2p[nbase+4],  n5 = W2p[nbase+5],  n6 = W2p[nbase+6],  n7 = W2p[nbase+7];
  PIN(g0); PIN(g1); PIN(g2); PIN(g3); PIN(g4); PIN(g5); PIN(g6); PIN(g7);
  PIN(g8); PIN(g9); PIN(gA); PIN(gB); PIN(gC); PIN(gD); PIN(gE); PIN(gF);
  PIN(n0); PIN(n1); PIN(n2); PIN(n3); PIN(n4); PIN(n5); PIN(n6); PIN(n7);

  float wir = Wih_f[i], wiz = Wih_f[HH + i], win = Wih_f[2*HH + i];
  float brs = bih_f[i]      + bhh_f[i];      // fold b_ih+b_hh for r
  float bzs = bih_f[HH + i] + bhh_f[HH + i]; // fold for z
  float bin = bih_f[2*HH + i];               // n: b_ih only
  float bhn = bhh_f[2*HH + i];               // n = tanh(xn + r*(dot+bhn))
  PIN(wir); PIN(wiz); PIN(win); PIN(brs); PIN(bzs); PIN(bin); PIN(bhn);

  float h = 0.0f;
  hbuf[w][k][i] = 0.0f;
  __builtin_amdgcn_wave_barrier();

  const vf4* hv  = (const vf4*)&hbuf[w][k][0];   // this half's copy: 8 x vf4 = h[0:32)
  const vf4* xv4 = (const vf4*)&xbuf[w][0];

  #pragma unroll 1
  for (int tg = 0; tg < TT / 4; ++tg) {
    const vf4 x4 = xv4[tg];                      // broadcast; 1 read per 4 steps
    #pragma unroll
    for (int u = 0; u < 4; ++u) {
      const float x = (u == 0) ? x4.x : (u == 1) ? x4.y : (u == 2) ? x4.z : x4.w;

      // all 32 h values, broadcast ds_read_b128 x8
      const vf4 H0 = hv[0], H1 = hv[1], H2 = hv[2], H3 = hv[3];
      const vf4 H4 = hv[4], H5 = hv[5], H6 = hv[6], H7 = hv[7];
      const vf2 p0 = {H0.x, H0.y}, p1 = {H0.z, H0.w};
      const vf2 p2 = {H1.x, H1.y}, p3 = {H1.z, H1.w};
      const vf2 p4 = {H2.x, H2.y}, p5 = {H2.z, H2.w};
      const vf2 p6 = {H3.x, H3.y}, p7 = {H3.z, H3.w};
      const vf2 p8 = {H4.x, H4.y}, p9 = {H4.z, H4.w};
      const vf2 pA = {H5.x, H5.y}, pB = {H5.z, H5.w};
      const vf2 pC = {H6.x, H6.y}, pD = {H6.z, H6.w};
      const vf2 pE = {H7.x, H7.y}, pF = {H7.z, H7.w};

      // full-gate dot (r for k=0, z for k=1): 16 pk FMA, 2 chains
      vf2 A0 = p0 * g0;
      vf2 A1 = p1 * g1;
      A0 = __builtin_elementwise_fma(p2, g2, A0);
      A1 = __builtin_elementwise_fma(p3, g3, A1);
      A0 = __builtin_elementwise_fma(p4, g4, A0);
      A1 = __builtin_elementwise_fma(p5, g5, A1);
      A0 = __builtin_elementwise_fma(p6, g6, A0);
      A1 = __builtin_elementwise_fma(p7, g7, A1);
      A0 = __builtin_elementwise_fma(p8, g8, A0);
      A1 = __builtin_elementwise_fma(p9, g9, A1);
      A0 = __builtin_elementwise_fma(pA, gA, A0);
      A1 = __builtin_elementwise_fma(pB, gB, A1);
      A0 = __builtin_elementwise_fma(pC, gC, A0);
      A1 = __builtin_elementwise_fma(pD, gD, A1);
      A0 = __builtin_elementwise_fma(pE, gE, A0);
      A1 = __builtin_elementwise_fma(pF, gF, A1);

      // n half-dot over this half's 16 h values: 8 pk FMA, 2 chains
      const vf2 q0 = k ? p8 : p0, q1 = k ? p9 : p1;
      const vf2 q2 = k ? pA : p2, q3 = k ? pB : p3;
      const vf2 q4 = k ? pC : p4, q5 = k ? pD : p5;
      const vf2 q6 = k ? pE : p6, q7 = k ? pF : p7;
      vf2 B0 = q0 * n0;
      vf2 B1 = q1 * n1;
      B0 = __builtin_elementwise_fma(q2, n2, B0);
      B1 = __builtin_elementwise_fma(q3, n3, B1);
      B0 = __builtin_elementwise_fma(q4, n4, B0);
      B1 = __builtin_elementwise_fma(q5, n5, B1);
      B0 = __builtin_elementwise_fma(q6, n6, B0);
      B1 = __builtin_elementwise_fma(q7, n7, B1);

      const vf2 As = A0 + A1;
      const float gdot = As.x + As.y;            // rdot (k=0) or zdot (k=1)
      const vf2 Bs = B0 + B1;
      const float nh = Bs.x + Bs.y;              // n half-dot

      const float other = __shfl_xor(gdot, 32, 64);
      const float rdot = k ? other : gdot;
      const float zdot = k ? gdot : other;
      const float ndot = nh + __shfl_xor(nh, 32, 64);

      const float r = sigm(__builtin_fmaf(x, wir, brs) + rdot);
      const float z = sigm(__builtin_fmaf(x, wiz, bzs) + zdot);
      const float n = tanh_(__builtin_fmaf(r, ndot + bhn, __builtin_fmaf(x, win, bin)));
      h = __builtin_fmaf(z, h - n, n);           // (1-z)*n + z*h

      hbuf[w][k][i] = h;                         // refresh this half's copy
      __builtin_amdgcn_wave_barrier();           // wave-synchronous LDS ordering
    }
  }

  // --- backward direction: exactly ONE GRU step from h0=0 on x[T-1] ---
  const float xl  = xbuf[w][TT - 1];
  const float rb  = sigm(__builtin_fmaf(xl, Wih_b[i],        bih_b[i]        + bhh_b[i]));
  const float zb  = sigm(__builtin_fmaf(xl, Wih_b[HH + i],   bih_b[HH + i]   + bhh_b[HH + i]));
  const float xnb =       __builtin_fmaf(xl, Wih_b[2*HH + i], bih_b[2*HH + i]);
  const float nb  = tanh_(__builtin_fmaf(rb, bhh_b[2*HH + i], xnb));
  const float hb  = nb - zb * nb;                // (1-zb)*nb + zb*0

  if (k == 0) obuf[w][i]      = h;               // h_f
  else        obuf[w][32 + i] = hb;              // h_b
  __builtin_amdgcn_wave_barrier();

  // --- MLP head: sigmoid(W2 @ relu(W1 @ [h_f,h_b] + b1) + b2) ---
  const int j = L & 15;                          // lanes 16..63 duplicate
  const vf4* W1r = (const vf4*)(W1 + j * 64);
  const vf4* hc  = (const vf4*)&obuf[w][0];
  vf4 a4 = W1r[0] * hc[0];
  #pragma unroll
  for (int q = 1; q < 16; ++q)
    a4 = __builtin_elementwise_fma(W1r[q], hc[q], a4);
  float acc = b1[j] + (a4.x + a4.y) + (a4.z + a4.w);
  float h1 = fmaxf(acc, 0.0f) * W2[j];
  h1 += __shfl_down(h1, 8, 16);
  h1 += __shfl_down(h1, 4, 16);
  h1 += __shfl_down(h1, 2, 16);
  h1 += __shfl_down(h1, 1, 16);
  if (L == 0) out[b] = sigm(h1 + b2[0]);
}

extern "C" void kernel_launch(void* const* d_in, const int* in_sizes, int n_in,
                              void* d_out, int out_size, void* d_ws, size_t ws_size,
                              hipStream_t stream) {
  const float* X     = (const float*)d_in[0];
  const float* Wih_f = (const float*)d_in[1];
  const float* Whh_f = (const float*)d_in[2];
  const float* bih_f = (const float*)d_in[3];
  const float* bhh_f = (const float*)d_in[4];
  const float* Wih_b = (const float*)d_in[5];
  // d_in[6] = W_hh_b: unused — backward direction runs exactly one step from h0=0.
  const float* bih_b = (const float*)d_in[7];
  const float* bhh_b = (const float*)d_in[8];
  const float* W1    = (const float*)d_in[9];
  const float* b1    = (const float*)d_in[10];
  const float* W2    = (const float*)d_in[11];
  const float* b2    = (const float*)d_in[12];
  float* out = (float*)d_out;

  // 2048 rows, 1 row per wave (64 lanes), 4 rows per 256-thread block
  // -> 512 blocks = 2 blocks/CU = 2 waves/SIMD.
  gru_bidir_head<<<512, 256, 0, stream>>>(X, Wih_f, Whh_f, bih_f, bhh_f,
                                          Wih_b, bih_b, bhh_b, W1, b1, W2, b2, out);
}

// Round 6
// 193.139 us; speedup vs baseline: 1.5672x; 1.5272x over previous
//
#include <hip/hip_runtime.h>

// Bidirectional GRU (H=32, input=1, B=2048, T=512) + MLP head, fully fused.
//
// Reference takes out[:, -1, :] = concat(h_fwd after T steps, h_bwd after ONE
// step from h0=0 on x[T-1]) -> only the forward scan is sequential; W_hh_b is
// entirely unused.
//
// R6 = R5 with the DOT16 macro-parameter/token-paste collision fixed
// (parameter "A" was pasted by P##A -> "WrRa").  Design rationale:
//
// R1-R4 post-mortem: the bottleneck is the per-step SERIAL CHAIN
// (1210 cyc/step/SIMD in R4), not weight residency (R4's pins held: 68 = 55
// pinned + 13 working) and not issue count.  R4's chain was inflated by (a)
// 2 serial DS-pipe shfls per step, (b) 8x ds_read_b128 serialized because
// only 13 free VGPRs couldn't hold the 32-reg read window.
//
// R5/R6 structure:
//   * 32 lanes per row, FULL 32-wide dot per lane (no shfl, no divergent
//     selects).  2 rows per wave as half-waves -> one instruction stream
//     drives both rows; 1024 waves = 1 wave/SIMD, chain-bound by design.
//   * Weights pinned via inline-asm "+v" (48 vf2 + 7 scalars, proven to hold
//     in R4).  The 16 h vf2-slices are ALSO pinned inside the loop so all 8
//     ds_read_b128 stay in flight together (~180 cyc, not 4x serialized).
//   * exp2-domain folding: W_r/W_z/biases pre-scaled by -log2(e), W_n/biases
//     by 2*log2(e) at load time.  sigmoid = v_rcp(1+v_exp2(dot)),
//     tanh = 1-2*v_rcp(1+v_exp2(dot)) -- minimal transcendental chain.
//   * x staged in LDS, consumed as vf4 every 4 steps (prefetched, off the
//     critical path).  h broadcast: ds_write_b32 + 8x broadcast ds_read_b128;
//     half-waves 2-way bank alias = free (m136).

typedef float vf2 __attribute__((ext_vector_type(2)));
typedef float vf4 __attribute__((ext_vector_type(4)));

#define TT 512
#define HH 32

// inline-asm defs are not rematerializable and not spill-friendly: forces
// the value to live in VGPRs at this point.
#define PIN(v) asm volatile("" : "+v"(v))

#define LOG2E 1.44269504f

__device__ __forceinline__ float fast_sigm(float a) {   // sigmoid(a)
  return __builtin_amdgcn_rcpf(1.0f + __builtin_amdgcn_exp2f(-LOG2E * a));
}
__device__ __forceinline__ float fast_tanh(float a) {   // tanh(a)
  return __builtin_fmaf(-2.0f,
      __builtin_amdgcn_rcpf(1.0f + __builtin_amdgcn_exp2f(2.0f * LOG2E * a)),
      1.0f);
}

// load one 32-float W_hh row as 16 vf2, pre-scaled, pinned
#define LD16(P, BASE, S) \
  vf2 P##0=Wp[(BASE)+0]*(S),  P##1=Wp[(BASE)+1]*(S),  P##2=Wp[(BASE)+2]*(S),  P##3=Wp[(BASE)+3]*(S), \
      P##4=Wp[(BASE)+4]*(S),  P##5=Wp[(BASE)+5]*(S),  P##6=Wp[(BASE)+6]*(S),  P##7=Wp[(BASE)+7]*(S), \
      P##8=Wp[(BASE)+8]*(S),  P##9=Wp[(BASE)+9]*(S),  P##A=Wp[(BASE)+10]*(S), P##B=Wp[(BASE)+11]*(S), \
      P##C=Wp[(BASE)+12]*(S), P##D=Wp[(BASE)+13]*(S), P##E=Wp[(BASE)+14]*(S), P##F=Wp[(BASE)+15]*(S); \
  PIN(P##0);PIN(P##1);PIN(P##2);PIN(P##3);PIN(P##4);PIN(P##5);PIN(P##6);PIN(P##7); \
  PIN(P##8);PIN(P##9);PIN(P##A);PIN(P##B);PIN(P##C);PIN(P##D);PIN(P##E);PIN(P##F)

// 16 pk-FMA dot of (q0..qF) . (P0..PF) into two chains X0,X1
// (parameter names X0/X1/P must not collide with pasted suffixes 0..F)
#define DOT16(X0, X1, P) \
  vf2 X0 = q0 * P##0;  vf2 X1 = q1 * P##1; \
  X0 = __builtin_elementwise_fma(q2, P##2, X0);  X1 = __builtin_elementwise_fma(q3, P##3, X1); \
  X0 = __builtin_elementwise_fma(q4, P##4, X0);  X1 = __builtin_elementwise_fma(q5, P##5, X1); \
  X0 = __builtin_elementwise_fma(q6, P##6, X0);  X1 = __builtin_elementwise_fma(q7, P##7, X1); \
  X0 = __builtin_elementwise_fma(q8, P##8, X0);  X1 = __builtin_elementwise_fma(q9, P##9, X1); \
  X0 = __builtin_elementwise_fma(qA, P##A, X0);  X1 = __builtin_elementwise_fma(qB, P##B, X1); \
  X0 = __builtin_elementwise_fma(qC, P##C, X0);  X1 = __builtin_elementwise_fma(qD, P##D, X1); \
  X0 = __builtin_elementwise_fma(qE, P##E, X0);  X1 = __builtin_elementwise_fma(qF, P##F, X1)

__global__ __launch_bounds__(256, 1)
void gru_bidir_head(const float* __restrict__ X,
                    const float* __restrict__ Wih_f, const float* __restrict__ Whh_f,
                    const float* __restrict__ bih_f, const float* __restrict__ bhh_f,
                    const float* __restrict__ Wih_b,
                    const float* __restrict__ bih_b, const float* __restrict__ bhh_b,
                    const float* __restrict__ W1, const float* __restrict__ b1,
                    const float* __restrict__ W2, const float* __restrict__ b2,
                    float* __restrict__ out)
{
  __shared__ float xbuf[8][TT];        // staged input rows (16 KB)
  __shared__ float hbuf[8][HH];        // h broadcast (1 KB)
  __shared__ float obuf[8][64];        // [row][h_f(32) | h_b(32)] (2 KB)

  const int g  = threadIdx.x & 31;     // lane within row group = output index i
  const int rs = threadIdx.x >> 5;     // row slot in block (0..7)
  const int b  = (blockIdx.x << 3) + rs;

  // --- stage this row of X into LDS (4 x vf4 per lane, coalesced) ---
  const vf4* Xr4 = (const vf4*)(X + (size_t)b * TT);
  vf4* xb4 = (vf4*)&xbuf[rs][0];
  #pragma unroll
  for (int q = 0; q < 4; ++q) xb4[g + 32 * q] = Xr4[g + 32 * q];

  // --- per-lane weights: W_hh rows g (r), 32+g (z), 64+g (n), pre-scaled ---
  const vf2* Wp = (const vf2*)Whh_f;   // row stride = 16 vf2
  const float s1 = -LOG2E;             // r,z: sigmoid in exp2 domain, negated
  const float s2 = 2.0f * LOG2E;       // n: tanh in exp2 domain
  LD16(Wr, g * 16, s1);
  LD16(Wz, (HH + g) * 16, s1);
  LD16(Wn, (2 * HH + g) * 16, s2);

  float xwr = Wih_f[g] * s1, xwz = Wih_f[HH + g] * s1, xwn = Wih_f[2*HH + g] * s2;
  float cbr = (bih_f[g]      + bhh_f[g])      * s1;
  float cbz = (bih_f[HH + g] + bhh_f[HH + g]) * s1;
  float cbn = bih_f[2*HH + g] * s2;            // n: b_ih term (with x)
  float cbh = bhh_f[2*HH + g] * s2;            // n: b_hh term (inside r*(...))
  PIN(xwr); PIN(xwz); PIN(xwn); PIN(cbr); PIN(cbz); PIN(cbn); PIN(cbh);

  float h = 0.0f;
  hbuf[rs][g] = 0.0f;
  __builtin_amdgcn_wave_barrier();

  const vf4* hv = (const vf4*)&hbuf[rs][0];
  const vf4* xv = (const vf4*)&xbuf[rs][0];
  vf4 x4 = xv[0];

  #pragma unroll 1
  for (int tg = 0; tg < TT / 4; ++tg) {
    const vf4 x4n = xv[tg + 1 < TT / 4 ? tg + 1 : tg];   // off critical path
    #pragma unroll
    for (int u = 0; u < 4; ++u) {
      const float x = (u == 0) ? x4.x : (u == 1) ? x4.y : (u == 2) ? x4.z : x4.w;

      // all 32 h values: 8 broadcast ds_read_b128
      vf4 H0 = hv[0], H1 = hv[1], H2 = hv[2], H3 = hv[3];
      vf4 H4 = hv[4], H5 = hv[5], H6 = hv[6], H7 = hv[7];
      vf2 q0 = {H0.x, H0.y}, q1 = {H0.z, H0.w}, q2 = {H1.x, H1.y}, q3 = {H1.z, H1.w},
          q4 = {H2.x, H2.y}, q5 = {H2.z, H2.w}, q6 = {H3.x, H3.y}, q7 = {H3.z, H3.w},
          q8 = {H4.x, H4.y}, q9 = {H4.z, H4.w}, qA = {H5.x, H5.y}, qB = {H5.z, H5.w},
          qC = {H6.x, H6.y}, qD = {H6.z, H6.w}, qE = {H7.x, H7.y}, qF = {H7.z, H7.w};
      // pin the whole window: forces all 8 b128 reads to be in flight
      // together instead of serialized through a tiny register window.
      asm volatile("" : "+v"(q0), "+v"(q1), "+v"(q2), "+v"(q3),
                        "+v"(q4), "+v"(q5), "+v"(q6), "+v"(q7),
                        "+v"(q8), "+v"(q9), "+v"(qA), "+v"(qB),
                        "+v"(qC), "+v"(qD), "+v"(qE), "+v"(qF));

      DOT16(Ra, Rb, Wr);
      DOT16(Za, Zb, Wz);
      DOT16(Na, Nb, Wn);

      const vf2 Rs = Ra + Rb;
      const vf2 Zs = Za + Zb;
      const vf2 Ns = Na + Nb;
      // r = sigmoid(xr+hr+b):  arg already = -log2e * (that sum)
      const float ar = __builtin_fmaf(x, xwr, cbr) + (Rs.x + Rs.y);
      const float az = __builtin_fmaf(x, xwz, cbz) + (Zs.x + Zs.y);
      const float r = __builtin_amdgcn_rcpf(1.0f + __builtin_amdgcn_exp2f(ar));
      const float z = __builtin_amdgcn_rcpf(1.0f + __builtin_amdgcn_exp2f(az));
      // n = tanh(xn + r*(hn+bhn)): arg already = 2*log2e * (that sum)
      const float y = __builtin_fmaf(r, (Ns.x + Ns.y) + cbh,
                                     __builtin_fmaf(x, xwn, cbn));
      const float n = __builtin_fmaf(-2.0f,
          __builtin_amdgcn_rcpf(1.0f + __builtin_amdgcn_exp2f(y)), 1.0f);
      h = __builtin_fmaf(z, h - n, n);           // (1-z)*n + z*h

      hbuf[rs][g] = h;                           // ds_write_b32
      __builtin_amdgcn_wave_barrier();           // wave-synchronous ordering
    }
    x4 = x4n;
  }

  // --- backward direction: exactly ONE GRU step from h0=0 on x[T-1] ---
  const float xl  = xbuf[rs][TT - 1];
  const float rb  = fast_sigm(__builtin_fmaf(xl, Wih_b[g],      bih_b[g]      + bhh_b[g]));
  const float zb  = fast_sigm(__builtin_fmaf(xl, Wih_b[HH + g], bih_b[HH + g] + bhh_b[HH + g]));
  const float xnb = __builtin_fmaf(xl, Wih_b[2*HH + g], bih_b[2*HH + g]);
  const float nb  = fast_tanh(__builtin_fmaf(rb, bhh_b[2*HH + g], xnb));
  const float hb  = nb - zb * nb;                // (1-zb)*nb + zb*0

  obuf[rs][g]      = h;                          // h_f
  obuf[rs][32 + g] = hb;                         // h_b
  __builtin_amdgcn_wave_barrier();

  // --- MLP head: sigmoid(W2 @ relu(W1 @ [h_f,h_b] + b1) + b2) ---
  const int j = g & 15;                          // lanes 16..31 duplicate
  const vf4* W1r = (const vf4*)(W1 + j * 64);
  const vf4* hc  = (const vf4*)&obuf[rs][0];
  vf4 a4 = W1r[0] * hc[0];
  #pragma unroll
  for (int q = 1; q < 16; ++q)
    a4 = __builtin_elementwise_fma(W1r[q], hc[q], a4);
  float acc = b1[j] + (a4.x + a4.y) + (a4.z + a4.w);
  float h1 = fmaxf(acc, 0.0f) * W2[j];
  h1 += __shfl_down(h1, 8, 16);
  h1 += __shfl_down(h1, 4, 16);
  h1 += __shfl_down(h1, 2, 16);
  h1 += __shfl_down(h1, 1, 16);
  if (g == 0) out[b] = fast_sigm(h1 + b2[0]);
}

extern "C" void kernel_launch(void* const* d_in, const int* in_sizes, int n_in,
                              void* d_out, int out_size, void* d_ws, size_t ws_size,
                              hipStream_t stream) {
  const float* X     = (const float*)d_in[0];
  const float* Wih_f = (const float*)d_in[1];
  const float* Whh_f = (const float*)d_in[2];
  const float* bih_f = (const float*)d_in[3];
  const float* bhh_f = (const float*)d_in[4];
  const float* Wih_b = (const float*)d_in[5];
  // d_in[6] = W_hh_b: unused — backward direction runs exactly one step from h0=0.
  const float* bih_b = (const float*)d_in[7];
  const float* bhh_b = (const float*)d_in[8];
  const float* W1    = (const float*)d_in[9];
  const float* b1    = (const float*)d_in[10];
  const float* W2    = (const float*)d_in[11];
  const float* b2    = (const float*)d_in[12];
  float* out = (float*)d_out;

  // 2048 rows / 8 rows per 256-thread block = 256 blocks = 1 block/CU,
  // 1024 waves = 1 wave/SIMD (2 rows per wave as half-waves).
  gru_bidir_head<<<256, 256, 0, stream>>>(X, Wih_f, Whh_f, bih_f, bhh_f,
                                          Wih_b, bih_b, bhh_b, W1, b1, W2, b2, out);
}

// Round 7
// 183.727 us; speedup vs baseline: 1.6474x; 1.0512x over previous
//
#include <hip/hip_runtime.h>

// Bidirectional GRU (H=32, input=1, B=2048, T=512) + MLP head, fully fused.
//
// Reference takes out[:, -1, :] = concat(h_fwd after T steps, h_bwd after ONE
// step from h0=0 on x[T-1]) -> only the forward scan is sequential; W_hh_b is
// entirely unused.
//
// R7 = R6 + __attribute__((amdgpu_waves_per_eu(1,1))).
//
// R6 post-mortem: VGPR_Count=80 < 96 regs of pinned weights -> PIN prevents
// remat but NOT spilling; the RA spilled the weights to scratch and reloads
// them in the loop (651 cyc/step vs ~250 chain estimate = ~2 serialized
// ~200-cyc L2 reload waits).  Root cause: __launch_bounds__' 2nd arg only
// sets MIN waves/EU; the scheduler still targets max occupancy (settled at
// 6 waves/EU = 80-reg budget) and prefers spilling over dropping occupancy.
// amdgpu_waves_per_eu(1,1) pins target occupancy to 1 wave/EU -> 512-reg
// budget -> weights + h-window resident, no spills.  We launch exactly
// 1 wave/SIMD anyway (256 blocks x 4 waves on 1024 SIMDs), so the HW
// occupancy cap costs nothing.
//
// Structure (unchanged from R6):
//   * 32 lanes per row, FULL 32-wide dot per lane (no shfl, no divergent
//     selects).  2 rows per wave as half-waves; chain-bound by design.
//   * Weights pinned via inline-asm "+v"; h-window (16 vf2) pinned inside
//     the loop so all 8 ds_read_b128 stay in flight together.
//   * exp2-domain folding: W_r/W_z pre-scaled by -log2(e), W_n by 2*log2(e);
//     sigmoid = v_rcp(1+v_exp2(.)), tanh = 1-2*v_rcp(1+v_exp2(.)).
//   * x staged in LDS, consumed as vf4 every 4 steps (prefetched).
//   * h broadcast: ds_write_b32 + 8x broadcast ds_read_b128 (conflict-free;
//     half-wave 2-way alias is free per m136).

typedef float vf2 __attribute__((ext_vector_type(2)));
typedef float vf4 __attribute__((ext_vector_type(4)));

#define TT 512
#define HH 32

// inline-asm defs are not rematerializable: forces a real VGPR def here.
#define PIN(v) asm volatile("" : "+v"(v))

#define LOG2E 1.44269504f

__device__ __forceinline__ float fast_sigm(float a) {   // sigmoid(a)
  return __builtin_amdgcn_rcpf(1.0f + __builtin_amdgcn_exp2f(-LOG2E * a));
}
__device__ __forceinline__ float fast_tanh(float a) {   // tanh(a)
  return __builtin_fmaf(-2.0f,
      __builtin_amdgcn_rcpf(1.0f + __builtin_amdgcn_exp2f(2.0f * LOG2E * a)),
      1.0f);
}

// load one 32-float W_hh row as 16 vf2, pre-scaled, pinned
#define LD16(P, BASE, S) \
  vf2 P##0=Wp[(BASE)+0]*(S),  P##1=Wp[(BASE)+1]*(S),  P##2=Wp[(BASE)+2]*(S),  P##3=Wp[(BASE)+3]*(S), \
      P##4=Wp[(BASE)+4]*(S),  P##5=Wp[(BASE)+5]*(S),  P##6=Wp[(BASE)+6]*(S),  P##7=Wp[(BASE)+7]*(S), \
      P##8=Wp[(BASE)+8]*(S),  P##9=Wp[(BASE)+9]*(S),  P##A=Wp[(BASE)+10]*(S), P##B=Wp[(BASE)+11]*(S), \
      P##C=Wp[(BASE)+12]*(S), P##D=Wp[(BASE)+13]*(S), P##E=Wp[(BASE)+14]*(S), P##F=Wp[(BASE)+15]*(S); \
  PIN(P##0);PIN(P##1);PIN(P##2);PIN(P##3);PIN(P##4);PIN(P##5);PIN(P##6);PIN(P##7); \
  PIN(P##8);PIN(P##9);PIN(P##A);PIN(P##B);PIN(P##C);PIN(P##D);PIN(P##E);PIN(P##F)

// 16 pk-FMA dot of (q0..qF) . (P0..PF) into two chains X0,X1
// (parameter names X0/X1/P must not collide with pasted suffixes 0..F)
#define DOT16(X0, X1, P) \
  vf2 X0 = q0 * P##0;  vf2 X1 = q1 * P##1; \
  X0 = __builtin_elementwise_fma(q2, P##2, X0);  X1 = __builtin_elementwise_fma(q3, P##3, X1); \
  X0 = __builtin_elementwise_fma(q4, P##4, X0);  X1 = __builtin_elementwise_fma(q5, P##5, X1); \
  X0 = __builtin_elementwise_fma(q6, P##6, X0);  X1 = __builtin_elementwise_fma(q7, P##7, X1); \
  X0 = __builtin_elementwise_fma(q8, P##8, X0);  X1 = __builtin_elementwise_fma(q9, P##9, X1); \
  X0 = __builtin_elementwise_fma(qA, P##A, X0);  X1 = __builtin_elementwise_fma(qB, P##B, X1); \
  X0 = __builtin_elementwise_fma(qC, P##C, X0);  X1 = __builtin_elementwise_fma(qD, P##D, X1); \
  X0 = __builtin_elementwise_fma(qE, P##E, X0);  X1 = __builtin_elementwise_fma(qF, P##F, X1)

__global__ __launch_bounds__(256)
__attribute__((amdgpu_waves_per_eu(1, 1)))
void gru_bidir_head(const float* __restrict__ X,
                    const float* __restrict__ Wih_f, const float* __restrict__ Whh_f,
                    const float* __restrict__ bih_f, const float* __restrict__ bhh_f,
                    const float* __restrict__ Wih_b,
                    const float* __restrict__ bih_b, const float* __restrict__ bhh_b,
                    const float* __restrict__ W1, const float* __restrict__ b1,
                    const float* __restrict__ W2, const float* __restrict__ b2,
                    float* __restrict__ out)
{
  __shared__ float xbuf[8][TT];        // staged input rows (16 KB)
  __shared__ float hbuf[8][HH];        // h broadcast (1 KB)
  __shared__ float obuf[8][64];        // [row][h_f(32) | h_b(32)] (2 KB)

  const int g  = threadIdx.x & 31;     // lane within row group = output index i
  const int rs = threadIdx.x >> 5;     // row slot in block (0..7)
  const int b  = (blockIdx.x << 3) + rs;

  // --- stage this row of X into LDS (4 x vf4 per lane, coalesced) ---
  const vf4* Xr4 = (const vf4*)(X + (size_t)b * TT);
  vf4* xb4 = (vf4*)&xbuf[rs][0];
  #pragma unroll
  for (int q = 0; q < 4; ++q) xb4[g + 32 * q] = Xr4[g + 32 * q];

  // --- per-lane weights: W_hh rows g (r), 32+g (z), 64+g (n), pre-scaled ---
  const vf2* Wp = (const vf2*)Whh_f;   // row stride = 16 vf2
  const float s1 = -LOG2E;             // r,z: sigmoid in exp2 domain, negated
  const float s2 = 2.0f * LOG2E;       // n: tanh in exp2 domain
  LD16(Wr, g * 16, s1);
  LD16(Wz, (HH + g) * 16, s1);
  LD16(Wn, (2 * HH + g) * 16, s2);

  float xwr = Wih_f[g] * s1, xwz = Wih_f[HH + g] * s1, xwn = Wih_f[2*HH + g] * s2;
  float cbr = (bih_f[g]      + bhh_f[g])      * s1;
  float cbz = (bih_f[HH + g] + bhh_f[HH + g]) * s1;
  float cbn = bih_f[2*HH + g] * s2;            // n: b_ih term (with x)
  float cbh = bhh_f[2*HH + g] * s2;            // n: b_hh term (inside r*(...))
  PIN(xwr); PIN(xwz); PIN(xwn); PIN(cbr); PIN(cbz); PIN(cbn); PIN(cbh);

  float h = 0.0f;
  hbuf[rs][g] = 0.0f;
  __builtin_amdgcn_wave_barrier();

  const vf4* hv = (const vf4*)&hbuf[rs][0];
  const vf4* xv = (const vf4*)&xbuf[rs][0];
  vf4 x4 = xv[0];

  #pragma unroll 1
  for (int tg = 0; tg < TT / 4; ++tg) {
    const vf4 x4n = xv[tg + 1 < TT / 4 ? tg + 1 : tg];   // off critical path
    #pragma unroll
    for (int u = 0; u < 4; ++u) {
      const float x = (u == 0) ? x4.x : (u == 1) ? x4.y : (u == 2) ? x4.z : x4.w;

      // all 32 h values: 8 broadcast ds_read_b128
      vf4 H0 = hv[0], H1 = hv[1], H2 = hv[2], H3 = hv[3];
      vf4 H4 = hv[4], H5 = hv[5], H6 = hv[6], H7 = hv[7];
      vf2 q0 = {H0.x, H0.y}, q1 = {H0.z, H0.w}, q2 = {H1.x, H1.y}, q3 = {H1.z, H1.w},
          q4 = {H2.x, H2.y}, q5 = {H2.z, H2.w}, q6 = {H3.x, H3.y}, q7 = {H3.z, H3.w},
          q8 = {H4.x, H4.y}, q9 = {H4.z, H4.w}, qA = {H5.x, H5.y}, qB = {H5.z, H5.w},
          qC = {H6.x, H6.y}, qD = {H6.z, H6.w}, qE = {H7.x, H7.y}, qF = {H7.z, H7.w};
      // pin the whole window: all 8 b128 reads in flight together
      asm volatile("" : "+v"(q0), "+v"(q1), "+v"(q2), "+v"(q3),
                        "+v"(q4), "+v"(q5), "+v"(q6), "+v"(q7),
                        "+v"(q8), "+v"(q9), "+v"(qA), "+v"(qB),
                        "+v"(qC), "+v"(qD), "+v"(qE), "+v"(qF));

      DOT16(Ra, Rb, Wr);
      DOT16(Za, Zb, Wz);
      DOT16(Na, Nb, Wn);

      const vf2 Rs = Ra + Rb;
      const vf2 Zs = Za + Zb;
      const vf2 Ns = Na + Nb;
      // r = sigmoid(xr+hr+b):  arg already = -log2e * (that sum)
      const float ar = __builtin_fmaf(x, xwr, cbr) + (Rs.x + Rs.y);
      const float az = __builtin_fmaf(x, xwz, cbz) + (Zs.x + Zs.y);
      const float r = __builtin_amdgcn_rcpf(1.0f + __builtin_amdgcn_exp2f(ar));
      const float z = __builtin_amdgcn_rcpf(1.0f + __builtin_amdgcn_exp2f(az));
      // n = tanh(xn + r*(hn+bhn)): arg already = 2*log2e * (that sum)
      const float y = __builtin_fmaf(r, (Ns.x + Ns.y) + cbh,
                                     __builtin_fmaf(x, xwn, cbn));
      const float n = __builtin_fmaf(-2.0f,
          __builtin_amdgcn_rcpf(1.0f + __builtin_amdgcn_exp2f(y)), 1.0f);
      h = __builtin_fmaf(z, h - n, n);           // (1-z)*n + z*h

      hbuf[rs][g] = h;                           // ds_write_b32
      __builtin_amdgcn_wave_barrier();           // wave-synchronous ordering
    }
    x4 = x4n;
  }

  // --- backward direction: exactly ONE GRU step from h0=0 on x[T-1] ---
  const float xl  = xbuf[rs][TT - 1];
  const float rb  = fast_sigm(__builtin_fmaf(xl, Wih_b[g],      bih_b[g]      + bhh_b[g]));
  const float zb  = fast_sigm(__builtin_fmaf(xl, Wih_b[HH + g], bih_b[HH + g] + bhh_b[HH + g]));
  const float xnb = __builtin_fmaf(xl, Wih_b[2*HH + g], bih_b[2*HH + g]);
  const float nb  = fast_tanh(__builtin_fmaf(rb, bhh_b[2*HH + g], xnb));
  const float hb  = nb - zb * nb;                // (1-zb)*nb + zb*0

  obuf[rs][g]      = h;                          // h_f
  obuf[rs][32 + g] = hb;                         // h_b
  __builtin_amdgcn_wave_barrier();

  // --- MLP head: sigmoid(W2 @ relu(W1 @ [h_f,h_b] + b1) + b2) ---
  const int j = g & 15;                          // lanes 16..31 duplicate
  const vf4* W1r = (const vf4*)(W1 + j * 64);
  const vf4* hc  = (const vf4*)&obuf[rs][0];
  vf4 a4 = W1r[0] * hc[0];
  #pragma unroll
  for (int q = 1; q < 16; ++q)
    a4 = __builtin_elementwise_fma(W1r[q], hc[q], a4);
  float acc = b1[j] + (a4.x + a4.y) + (a4.z + a4.w);
  float h1 = fmaxf(acc, 0.0f) * W2[j];
  h1 += __shfl_down(h1, 8, 16);
  h1 += __shfl_down(h1, 4, 16);
  h1 += __shfl_down(h1, 2, 16);
  h1 += __shfl_down(h1, 1, 16);
  if (g == 0) out[b] = fast_sigm(h1 + b2[0]);
}

extern "C" void kernel_launch(void* const* d_in, const int* in_sizes, int n_in,
                              void* d_out, int out_size, void* d_ws, size_t ws_size,
                              hipStream_t stream) {
  const float* X     = (const float*)d_in[0];
  const float* Wih_f = (const float*)d_in[1];
  const float* Whh_f = (const float*)d_in[2];
  const float* bih_f = (const float*)d_in[3];
  const float* bhh_f = (const float*)d_in[4];
  const float* Wih_b = (const float*)d_in[5];
  // d_in[6] = W_hh_b: unused — backward direction runs exactly one step from h0=0.
  const float* bih_b = (const float*)d_in[7];
  const float* bhh_b = (const float*)d_in[8];
  const float* W1    = (const float*)d_in[9];
  const float* b1    = (const float*)d_in[10];
  const float* W2    = (const float*)d_in[11];
  const float* b2    = (const float*)d_in[12];
  float* out = (float*)d_out;

  // 2048 rows / 8 rows per 256-thread block = 256 blocks = 1 block/CU,
  // 1024 waves = 1 wave/SIMD (2 rows per wave as half-waves).
  gru_bidir_head<<<256, 256, 0, stream>>>(X, Wih_f, Whh_f, bih_f, bhh_f,
                                          Wih_b, bih_b, bhh_b, W1, b1, W2, b2, out);
}

// Round 8
// 177.787 us; speedup vs baseline: 1.7025x; 1.0334x over previous
//
#include <hip/hip_runtime.h>

// Bidirectional GRU (H=32, input=1, B=2048, T=512) + MLP head, fully fused.
//
// Reference takes out[:, -1, :] = concat(h_fwd after T steps, h_bwd after ONE
// step from h0=0 on x[T-1]) -> only the forward scan is sequential; W_hh_b is
// entirely unused.
//
// R8 = R7 with the recurrent dot in f16 v_dot2_f32_f16.
//
// R7 post-mortem: VGPR=132 with waves_per_eu(1,1); the ~25 vf2 that didn't
// fit were spilled to AGPRs (unified file) -> ~96 v_accvgpr_read per step =
// the observed ~340 cyc VALU issue (vs ~170 clean).  Fix: halve the
// footprint.  f16 dot2 keeps f32 accumulation; weights become 48 VGPRs of
// packed f16 (96 halves), h-window 16 VGPRs (32 halves, 4x ds_read_b128).
// Total ~95 regs -> fully resident, no AGPR tax.  Precision: f16 rel err
// 2.4e-4 with f32 accumulate -> per-step h error ~1e-4, damped by the GRU
// recurrence; h state itself stays fp32 (only the LDS broadcast copy is f16).
//
// Structure (else unchanged from R7):
//   * 32 lanes per row, full 32-wide dot per lane, no shfl.  2 rows per wave
//     as half-waves; 1024 waves = 1 wave/SIMD; chain-bound by design.
//   * exp2-domain folding: W_r/W_z pre-scaled by -log2(e), W_n by 2*log2(e);
//     sigmoid = v_rcp(1+v_exp2(.)), tanh = 1-2*v_rcp(1+v_exp2(.)).
//   * x staged in LDS (f32), consumed as vf4 every 4 steps.
//   * h broadcast: v_cvt + ds_write_b16, then 4x broadcast ds_read_b128;
//     half-waves hit disjoint bank groups (row stride 64 B) -> conflict-free.

typedef float vf2 __attribute__((ext_vector_type(2)));
typedef float vf4 __attribute__((ext_vector_type(4)));
typedef _Float16 f16;
typedef f16 h2 __attribute__((ext_vector_type(2)));
typedef f16 h8 __attribute__((ext_vector_type(8)));

#define TT 512
#define HH 32

// inline-asm defs are not rematerializable: forces a real VGPR def here.
#define PIN(v) asm volatile("" : "+v"(v))

#define LOG2E 1.44269504f

__device__ __forceinline__ float fast_sigm(float a) {   // sigmoid(a)
  return __builtin_amdgcn_rcpf(1.0f + __builtin_amdgcn_exp2f(-LOG2E * a));
}
__device__ __forceinline__ float fast_tanh(float a) {   // tanh(a)
  return __builtin_fmaf(-2.0f,
      __builtin_amdgcn_rcpf(1.0f + __builtin_amdgcn_exp2f(2.0f * LOG2E * a)),
      1.0f);
}

__device__ __forceinline__ h2 pack_h2(vf2 a, float s) {
  h2 r = {(f16)(a.x * s), (f16)(a.y * s)};
  return r;
}

// load one 32-float W_hh row as 16 packed-f16 h2 regs, pre-scaled, pinned
#define LDW16(P, BASE, S) \
  h2 P##0=pack_h2(Wp[(BASE)+0],(S)),  P##1=pack_h2(Wp[(BASE)+1],(S)), \
     P##2=pack_h2(Wp[(BASE)+2],(S)),  P##3=pack_h2(Wp[(BASE)+3],(S)), \
     P##4=pack_h2(Wp[(BASE)+4],(S)),  P##5=pack_h2(Wp[(BASE)+5],(S)), \
     P##6=pack_h2(Wp[(BASE)+6],(S)),  P##7=pack_h2(Wp[(BASE)+7],(S)), \
     P##8=pack_h2(Wp[(BASE)+8],(S)),  P##9=pack_h2(Wp[(BASE)+9],(S)), \
     P##A=pack_h2(Wp[(BASE)+10],(S)), P##B=pack_h2(Wp[(BASE)+11],(S)), \
     P##C=pack_h2(Wp[(BASE)+12],(S)), P##D=pack_h2(Wp[(BASE)+13],(S)), \
     P##E=pack_h2(Wp[(BASE)+14],(S)), P##F=pack_h2(Wp[(BASE)+15],(S)); \
  PIN(P##0);PIN(P##1);PIN(P##2);PIN(P##3);PIN(P##4);PIN(P##5);PIN(P##6);PIN(P##7); \
  PIN(P##8);PIN(P##9);PIN(P##A);PIN(P##B);PIN(P##C);PIN(P##D);PIN(P##E);PIN(P##F)

// 16 v_dot2_f32_f16 of (q0..qF).(P0..PF) into two chains A0,A1; A0 seeded.
#define FDOT16(A0, A1, P, SEED) \
  float A0 = __builtin_amdgcn_fdot2(q0, P##0, (SEED), false); \
  float A1 = __builtin_amdgcn_fdot2(q1, P##1, 0.0f, false); \
  A0 = __builtin_amdgcn_fdot2(q2, P##2, A0, false);  A1 = __builtin_amdgcn_fdot2(q3, P##3, A1, false); \
  A0 = __builtin_amdgcn_fdot2(q4, P##4, A0, false);  A1 = __builtin_amdgcn_fdot2(q5, P##5, A1, false); \
  A0 = __builtin_amdgcn_fdot2(q6, P##6, A0, false);  A1 = __builtin_amdgcn_fdot2(q7, P##7, A1, false); \
  A0 = __builtin_amdgcn_fdot2(q8, P##8, A0, false);  A1 = __builtin_amdgcn_fdot2(q9, P##9, A1, false); \
  A0 = __builtin_amdgcn_fdot2(qA, P##A, A0, false);  A1 = __builtin_amdgcn_fdot2(qB, P##B, A1, false); \
  A0 = __builtin_amdgcn_fdot2(qC, P##C, A0, false);  A1 = __builtin_amdgcn_fdot2(qD, P##D, A1, false); \
  A0 = __builtin_amdgcn_fdot2(qE, P##E, A0, false);  A1 = __builtin_amdgcn_fdot2(qF, P##F, A1, false)

__global__ __launch_bounds__(256)
__attribute__((amdgpu_waves_per_eu(1, 1)))
void gru_bidir_head(const float* __restrict__ X,
                    const float* __restrict__ Wih_f, const float* __restrict__ Whh_f,
                    const float* __restrict__ bih_f, const float* __restrict__ bhh_f,
                    const float* __restrict__ Wih_b,
                    const float* __restrict__ bih_b, const float* __restrict__ bhh_b,
                    const float* __restrict__ W1, const float* __restrict__ b1,
                    const float* __restrict__ W2, const float* __restrict__ b2,
                    float* __restrict__ out)
{
  __shared__ float xbuf[8][TT];        // staged input rows (16 KB)
  __shared__ f16   hbuf[8][HH];        // h broadcast, f16 (512 B)
  __shared__ float obuf[8][64];        // [row][h_f(32) | h_b(32)] (2 KB)

  const int g  = threadIdx.x & 31;     // lane within row group = output index i
  const int rs = threadIdx.x >> 5;     // row slot in block (0..7)
  const int b  = (blockIdx.x << 3) + rs;

  // --- stage this row of X into LDS (4 x vf4 per lane, coalesced) ---
  const vf4* Xr4 = (const vf4*)(X + (size_t)b * TT);
  vf4* xb4 = (vf4*)&xbuf[rs][0];
  #pragma unroll
  for (int q = 0; q < 4; ++q) xb4[g + 32 * q] = Xr4[g + 32 * q];

  // --- per-lane weights: W_hh rows g (r), 32+g (z), 64+g (n); pre-scaled,
  //     packed to f16, pinned (48 VGPRs total) ---
  const vf2* Wp = (const vf2*)Whh_f;   // row stride = 16 vf2
  const float s1 = -LOG2E;             // r,z: sigmoid in exp2 domain, negated
  const float s2 = 2.0f * LOG2E;       // n: tanh in exp2 domain
  LDW16(Wr, g * 16, s1);
  LDW16(Wz, (HH + g) * 16, s1);
  LDW16(Wn, (2 * HH + g) * 16, s2);

  float xwr = Wih_f[g] * s1, xwz = Wih_f[HH + g] * s1, xwn = Wih_f[2*HH + g] * s2;
  float cbr = (bih_f[g]      + bhh_f[g])      * s1;
  float cbz = (bih_f[HH + g] + bhh_f[HH + g]) * s1;
  float cbn = bih_f[2*HH + g] * s2;            // n: b_ih term (with x)
  float cbh = bhh_f[2*HH + g] * s2;            // n: b_hh term (inside r*(...))
  PIN(xwr); PIN(xwz); PIN(xwn); PIN(cbr); PIN(cbz); PIN(cbn); PIN(cbh);

  float h = 0.0f;
  hbuf[rs][g] = (f16)0.0f;
  __builtin_amdgcn_wave_barrier();

  const h8*  hv = (const h8*)&hbuf[rs][0];     // 4 x b128 = all 32 f16 h
  const vf4* xv = (const vf4*)&xbuf[rs][0];
  vf4 x4 = xv[0];

  #pragma unroll 1
  for (int tg = 0; tg < TT / 4; ++tg) {
    const vf4 x4n = xv[tg + 1 < TT / 4 ? tg + 1 : tg];   // off critical path
    #pragma unroll
    for (int u = 0; u < 4; ++u) {
      const float x = (u == 0) ? x4.x : (u == 1) ? x4.y : (u == 2) ? x4.z : x4.w;

      // all 32 h (f16): 4 broadcast ds_read_b128
      h8 H0 = hv[0], H1 = hv[1], H2 = hv[2], H3 = hv[3];
      h2 q0 = {H0[0], H0[1]}, q1 = {H0[2], H0[3]}, q2 = {H0[4], H0[5]}, q3 = {H0[6], H0[7]},
         q4 = {H1[0], H1[1]}, q5 = {H1[2], H1[3]}, q6 = {H1[4], H1[5]}, q7 = {H1[6], H1[7]},
         q8 = {H2[0], H2[1]}, q9 = {H2[2], H2[3]}, qA = {H2[4], H2[5]}, qB = {H2[6], H2[7]},
         qC = {H3[0], H3[1]}, qD = {H3[2], H3[3]}, qE = {H3[4], H3[5]}, qF = {H3[6], H3[7]};
      // pin the window: all 4 b128 reads in flight together
      asm volatile("" : "+v"(q0), "+v"(q1), "+v"(q2), "+v"(q3),
                        "+v"(q4), "+v"(q5), "+v"(q6), "+v"(q7),
                        "+v"(q8), "+v"(q9), "+v"(qA), "+v"(qB),
                        "+v"(qC), "+v"(qD), "+v"(qE), "+v"(qF));

      FDOT16(Ra, Rb, Wr, __builtin_fmaf(x, xwr, cbr));
      FDOT16(Za, Zb, Wz, __builtin_fmaf(x, xwz, cbz));
      FDOT16(Na, Nb, Wn, cbh);

      const float ar = Ra + Rb;                  // already includes x-term+bias
      const float az = Za + Zb;
      const float r = __builtin_amdgcn_rcpf(1.0f + __builtin_amdgcn_exp2f(ar));
      const float z = __builtin_amdgcn_rcpf(1.0f + __builtin_amdgcn_exp2f(az));
      const float y = __builtin_fmaf(r, Na + Nb, __builtin_fmaf(x, xwn, cbn));
      const float n = __builtin_fmaf(-2.0f,
          __builtin_amdgcn_rcpf(1.0f + __builtin_amdgcn_exp2f(y)), 1.0f);
      h = __builtin_fmaf(z, h - n, n);           // (1-z)*n + z*h

      hbuf[rs][g] = (f16)h;                      // v_cvt + ds_write_b16
      __builtin_amdgcn_wave_barrier();           // wave-synchronous ordering
    }
    x4 = x4n;
  }

  // --- backward direction: exactly ONE GRU step from h0=0 on x[T-1] ---
  const float xl  = xbuf[rs][TT - 1];
  const float rb  = fast_sigm(__builtin_fmaf(xl, Wih_b[g],      bih_b[g]      + bhh_b[g]));
  const float zb  = fast_sigm(__builtin_fmaf(xl, Wih_b[HH + g], bih_b[HH + g] + bhh_b[HH + g]));
  const float xnb = __builtin_fmaf(xl, Wih_b[2*HH + g], bih_b[2*HH + g]);
  const float nb  = fast_tanh(__builtin_fmaf(rb, bhh_b[2*HH + g], xnb));
  const float hb  = nb - zb * nb;                // (1-zb)*nb + zb*0

  obuf[rs][g]      = h;                          // h_f (full fp32 state)
  obuf[rs][32 + g] = hb;                         // h_b
  __builtin_amdgcn_wave_barrier();

  // --- MLP head: sigmoid(W2 @ relu(W1 @ [h_f,h_b] + b1) + b2) ---
  const int j = g & 15;                          // lanes 16..31 duplicate
  const vf4* W1r = (const vf4*)(W1 + j * 64);
  const vf4* hc  = (const vf4*)&obuf[rs][0];
  vf4 a4 = W1r[0] * hc[0];
  #pragma unroll
  for (int q = 1; q < 16; ++q)
    a4 = __builtin_elementwise_fma(W1r[q], hc[q], a4);
  float acc = b1[j] + (a4.x + a4.y) + (a4.z + a4.w);
  float h1 = fmaxf(acc, 0.0f) * W2[j];
  h1 += __shfl_down(h1, 8, 16);
  h1 += __shfl_down(h1, 4, 16);
  h1 += __shfl_down(h1, 2, 16);
  h1 += __shfl_down(h1, 1, 16);
  if (g == 0) out[b] = fast_sigm(h1 + b2[0]);
}

extern "C" void kernel_launch(void* const* d_in, const int* in_sizes, int n_in,
                              void* d_out, int out_size, void* d_ws, size_t ws_size,
                              hipStream_t stream) {
  const float* X     = (const float*)d_in[0];
  const float* Wih_f = (const float*)d_in[1];
  const float* Whh_f = (const float*)d_in[2];
  const float* bih_f = (const float*)d_in[3];
  const float* bhh_f = (const float*)d_in[4];
  const float* Wih_b = (const float*)d_in[5];
  // d_in[6] = W_hh_b: unused — backward direction runs exactly one step from h0=0.
  const float* bih_b = (const float*)d_in[7];
  const float* bhh_b = (const float*)d_in[8];
  const float* W1    = (const float*)d_in[9];
  const float* b1    = (const float*)d_in[10];
  const float* W2    = (const float*)d_in[11];
  const float* b2    = (const float*)d_in[12];
  float* out = (float*)d_out;

  // 2048 rows / 8 rows per 256-thread block = 256 blocks = 1 block/CU,
  // 1024 waves = 1 wave/SIMD (2 rows per wave as half-waves).
  gru_bidir_head<<<256, 256, 0, stream>>>(X, Wih_f, Whh_f, bih_f, bhh_f,
                                          Wih_b, bih_b, bhh_b, W1, b1, W2, b2, out);
}